// Round 2
// baseline (3819.771 us; speedup 1.0000x reference)
//
#include <hip/hip_runtime.h>
#include <hip/hip_bf16.h>

#define BN_EPS 1e-4f

__device__ __forceinline__ int rfl(int x) { return __builtin_amdgcn_readfirstlane(x); }

__device__ __forceinline__ float ldf(const float* p) { return *p; }
__device__ __forceinline__ float ldf(const __hip_bfloat16* p) { return __bfloat162float(*p); }
__device__ __forceinline__ void stf(float* p, float v) { *p = v; }
__device__ __forceinline__ void stf(__hip_bfloat16* p, float v) { *p = __float2bfloat16(v); }

// ---------------- xv = subconv(feats[N,3], nbr_fine, W_sub[27,3,32]) ----------------
// Thread-per-row: CIN=3 too ragged for lane-splitting; total work tiny. fp32 out.
__global__ __launch_bounds__(256) void k_xv(const float* __restrict__ feats,
                                            const int* __restrict__ nbr,
                                            const float* __restrict__ W,
                                            float* __restrict__ out, int N) {
    int n = blockIdx.x * 256 + threadIdx.x;
    if (n >= N) return;
    float acc[32];
#pragma unroll
    for (int d = 0; d < 32; ++d) acc[d] = 0.f;
    const int* nb = nbr + (size_t)n * 27;
    for (int k = 0; k < 27; ++k) {
        int idx = nb[k];
        if (idx < 0) continue;
        float f0 = feats[(size_t)idx * 3 + 0];
        float f1 = feats[(size_t)idx * 3 + 1];
        float f2 = feats[(size_t)idx * 3 + 2];
        const float* w = W + k * 96;  // k uniform -> scalar loads
#pragma unroll
        for (int d = 0; d < 32; ++d)
            acc[d] += f0 * w[d] + f1 * w[32 + d] + f2 * w[64 + d];
    }
    float4* o = (float4*)(out + (size_t)n * 32);
#pragma unroll
    for (int j = 0; j < 8; ++j)
        o[j] = make_float4(acc[4 * j], acc[4 * j + 1], acc[4 * j + 2], acc[4 * j + 3]);
}

// ---------------- generic wave-per-row submanifold conv ----------------
// lane = split*(COUT/4) + d4; each lane accumulates float4 of outputs over its
// c-chunk; cross-split shfl_xor reduction. Tap-validity branch is wave-uniform
// (zero divergence waste on ~94%-empty taps). BN stats (sum,sumsq) accumulated
// from fp32 pre-store values. SPLIT: input channels come from two stride-32
// buffers (e0 | up) instead of one contiguous stride-CIN buffer.
template <int CIN, int COUT, bool SPLIT, typename TIN, typename TOUT>
__global__ __launch_bounds__(256) void k_subconv(const TIN* __restrict__ inA,
                                                 const TIN* __restrict__ inB,
                                                 const int* __restrict__ nbr,
                                                 const float* __restrict__ W,
                                                 TOUT* __restrict__ out, int nrows,
                                                 float* __restrict__ ssum,
                                                 float* __restrict__ ssq) {
    constexpr int DQ = COUT / 4;      // float4 output groups
    constexpr int NSPLIT = 64 / DQ;   // c-chunks
    constexpr int CCH = CIN / NSPLIT; // c per chunk
    const int lane = threadIdx.x & 63;
    const int split = lane / DQ;
    const int d4 = lane % DQ;
    int wid = blockIdx.x * 4 + (threadIdx.x >> 6);
    int nw = gridDim.x * 4;
    float s0 = 0.f, s1 = 0.f, s2 = 0.f, s3 = 0.f;
    float q0 = 0.f, q1 = 0.f, q2 = 0.f, q3 = 0.f;
    for (int row = wid; row < nrows; row += nw) {
        int urow = rfl(row);
        float ax = 0.f, ay = 0.f, az = 0.f, aw = 0.f;
        const int* nb = nbr + (size_t)urow * 27;
        for (int k = 0; k < 27; ++k) {
            int idx = rfl(nb[k]);
            if (idx < 0) continue;  // wave-uniform skip
            float f;
            if (SPLIT)
                f = (lane < 32) ? ldf(inA + (size_t)idx * 32 + lane)
                                : ldf(inB + (size_t)idx * 32 + lane - 32);
            else
                f = (CIN == 64 || lane < CIN) ? ldf(inA + (size_t)idx * CIN + lane) : 0.f;
            const float4* w4 = (const float4*)(W + ((size_t)k * CIN + split * CCH) * COUT) + d4;
#pragma unroll
            for (int i = 0; i < CCH; ++i) {
                float fv = __shfl(f, split * CCH + i);
                float4 wv = w4[i * DQ];
                ax = fmaf(fv, wv.x, ax); ay = fmaf(fv, wv.y, ay);
                az = fmaf(fv, wv.z, az); aw = fmaf(fv, wv.w, aw);
            }
        }
#pragma unroll
        for (int off = DQ; off < 64; off <<= 1) {
            ax += __shfl_xor(ax, off);
            ay += __shfl_xor(ay, off);
            az += __shfl_xor(az, off);
            aw += __shfl_xor(aw, off);
        }
        if (split == 0) {
            TOUT* ob = out + (size_t)urow * COUT + d4 * 4;
            stf(ob + 0, ax); stf(ob + 1, ay); stf(ob + 2, az); stf(ob + 3, aw);
            s0 += ax; s1 += ay; s2 += az; s3 += aw;
            q0 += ax * ax; q1 += ay * ay; q2 += az * az; q3 += aw * aw;
        }
    }
    if (split == 0) {
        atomicAdd(&ssum[d4 * 4 + 0], s0);
        atomicAdd(&ssum[d4 * 4 + 1], s1);
        atomicAdd(&ssum[d4 * 4 + 2], s2);
        atomicAdd(&ssum[d4 * 4 + 3], s3);
        atomicAdd(&ssq[d4 * 4 + 0], q0);
        atomicAdd(&ssq[d4 * 4 + 1], q1);
        atomicAdd(&ssq[d4 * 4 + 2], q2);
        atomicAdd(&ssq[d4 * 4 + 3], q3);
    }
}

// ---------------- BN finalize: scale/shift from sums ----------------
__global__ void k_fin(const float* __restrict__ ssum, const float* __restrict__ ssq,
                      const float* __restrict__ g, const float* __restrict__ b,
                      float* __restrict__ scale, float* __restrict__ shift,
                      int C, float invN) {
    int c = blockIdx.x * blockDim.x + threadIdx.x;
    if (c >= C) return;
    float mu = ssum[c] * invN;
    float var = fmaxf(ssq[c] * invN - mu * mu, 0.f);
    float s = g[c] * rsqrtf(var + BN_EPS);
    scale[c] = s;
    shift[c] = b[c] - mu * s;
}

// ---- e0 = bnrelu(e0raw) in place (bf16); down[parent] += e0 @ W_down[off] (fp32 atomics) ----
__global__ __launch_bounds__(256) void k_down(__hip_bfloat16* __restrict__ e0,
                                              const int* __restrict__ parent,
                                              const int* __restrict__ child,
                                              const float* __restrict__ Wd,
                                              const float* __restrict__ sc,
                                              const float* __restrict__ sh,
                                              float* __restrict__ down, int N) {
    const int lane = threadIdx.x & 63;
    int wid = blockIdx.x * 4 + (threadIdx.x >> 6);
    int nw = gridDim.x * 4;
    for (int row = wid; row < N; row += nw) {
        int urow = rfl(row);
        float v = 0.f;
        if (lane < 32) {
            float r = ldf(e0 + (size_t)urow * 32 + lane);
            v = fmaxf(fmaf(r, sc[lane], sh[lane]), 0.f);
            stf(e0 + (size_t)urow * 32 + lane, v);  // post-BN e0, consumed by dec
        }
        int par = rfl(parent[urow]);
        int off = rfl(child[urow]);
        float acc = 0.f;
        const float* wb = Wd + (size_t)off * 2048 + lane;  // W_down[off][c][lane]
#pragma unroll
        for (int c = 0; c < 32; ++c)
            acc = fmaf(__shfl(v, c), wb[c * 64], acc);
        atomicAdd(&down[(size_t)par * 64 + lane], acc);
    }
}

// ---- up[n] = bnrelu(e1raw)[parent[n]] @ W_up[off[n]] -> bf16 ----
__global__ __launch_bounds__(256) void k_up(const __hip_bfloat16* __restrict__ e1raw,
                                            const int* __restrict__ parent,
                                            const int* __restrict__ child,
                                            const float* __restrict__ Wu,
                                            const float* __restrict__ sc,
                                            const float* __restrict__ sh,
                                            __hip_bfloat16* __restrict__ up, int N) {
    const int lane = threadIdx.x & 63;
    int wid = blockIdx.x * 4 + (threadIdx.x >> 6);
    int nw = gridDim.x * 4;
    for (int row = wid; row < N; row += nw) {
        int urow = rfl(row);
        int par = rfl(parent[urow]);
        int off = rfl(child[urow]);
        float e = ldf(e1raw + (size_t)par * 64 + lane);
        float v = fmaxf(fmaf(e, sc[lane], sh[lane]), 0.f);  // BN on the fly
        int d = lane & 31, hi = lane >> 5;
        float acc = 0.f;
        const float* wb = Wu + (size_t)off * 2048 + (size_t)hi * 1024 + d;
#pragma unroll
        for (int c = 0; c < 32; ++c)
            acc = fmaf(__shfl(v, hi * 32 + c), wb[c * 32], acc);
        acc += __shfl_xor(acc, 32);
        if (hi == 0) stf(up + (size_t)urow * 32 + d, acc);
    }
}

// ---- feature = bnrelu(decraw); y = feature @ W_lin + b_lin ----
__global__ __launch_bounds__(256) void k_out(const __hip_bfloat16* __restrict__ dec,
                                             const float* __restrict__ sc,
                                             const float* __restrict__ sh,
                                             const float* __restrict__ Wl,
                                             const float* __restrict__ bl,
                                             float* __restrict__ y,
                                             float* __restrict__ feat, int N) {
    int n = blockIdx.x * 256 + threadIdx.x;
    if (n >= N) return;
    float f[32];
    const __hip_bfloat162* p = (const __hip_bfloat162*)(dec + (size_t)n * 32);
#pragma unroll
    for (int j = 0; j < 16; ++j) {
        float2 t = __bfloat1622float2(p[j]);
        f[2 * j + 0] = fmaxf(fmaf(t.x, sc[2 * j + 0], sh[2 * j + 0]), 0.f);
        f[2 * j + 1] = fmaxf(fmaf(t.y, sc[2 * j + 1], sh[2 * j + 1]), 0.f);
    }
    float4* fo = (float4*)(feat + (size_t)n * 32);
#pragma unroll
    for (int j = 0; j < 8; ++j)
        fo[j] = make_float4(f[4 * j], f[4 * j + 1], f[4 * j + 2], f[4 * j + 3]);
    float acc[20];
#pragma unroll
    for (int q = 0; q < 20; ++q) acc[q] = bl[q];
#pragma unroll
    for (int c = 0; c < 32; ++c) {
        float fc = f[c];
#pragma unroll
        for (int q = 0; q < 20; ++q) acc[q] = fmaf(fc, Wl[c * 20 + q], acc[q]);
    }
    float4* yo = (float4*)(y + (size_t)n * 20);
#pragma unroll
    for (int j = 0; j < 5; ++j)
        yo[j] = make_float4(acc[4 * j], acc[4 * j + 1], acc[4 * j + 2], acc[4 * j + 3]);
}

extern "C" void kernel_launch(void* const* d_in, const int* in_sizes, int n_in,
                              void* d_out, int out_size, void* d_ws, size_t ws_size,
                              hipStream_t stream) {
    const float* feats = (const float*)d_in[0];
    const int* nbr_f   = (const int*)d_in[1];
    const int* nbr_c   = (const int*)d_in[2];
    const int* parent  = (const int*)d_in[3];
    const int* child   = (const int*)d_in[4];
    const float* W_sub = (const float*)d_in[5];
    const float* W_e0  = (const float*)d_in[6];
    const float* g0    = (const float*)d_in[7];
    const float* b0    = (const float*)d_in[8];
    const float* W_dn  = (const float*)d_in[9];
    const float* W_e1  = (const float*)d_in[10];
    const float* g1    = (const float*)d_in[11];
    const float* b1    = (const float*)d_in[12];
    const float* W_up  = (const float*)d_in[13];
    const float* W_dec = (const float*)d_in[14];
    const float* g_o   = (const float*)d_in[15];
    const float* b_o   = (const float*)d_in[16];
    const float* W_lin = (const float*)d_in[17];
    const float* b_lin = (const float*)d_in[18];

    const int N = in_sizes[0] / 3;
    const int M = in_sizes[2] / 27;

    // --- workspace (94.3 MB): overlapped live ranges ---
    // [0 .. R): xv fp32 (N*32, steps 1-2)  /  down fp32 (M*64, steps 4-5)
    //           up bf16 at [0..N*16) + decraw bf16 at [N*16..N*32) (steps 7-10)
    // [R .. R+512): BN stats
    float* wsf = (float*)d_ws;
    size_t R = (size_t)M * 64;
    if ((size_t)N * 32 > R) R = (size_t)N * 32;
    float* xv   = wsf;
    float* down = wsf;
    __hip_bfloat16* up     = (__hip_bfloat16*)wsf;
    __hip_bfloat16* decraw = (__hip_bfloat16*)(wsf + (size_t)N * 16);
    float* stats = wsf + R;
    // stats map: 0 sum0[32] | 32 sq0[32] | 64 sum1[64] | 128 sq1[64] |
    //            192 sumo[32] | 224 sqo[32] | 256 scale0 | 288 shift0 |
    //            320 scale1[64] | 384 shift1[64] | 448 scaleo | 480 shifto

    // --- d_out doubles as scratch: e0 bf16 [0..N*16 floats), e1raw bf16
    // [N*16..N*16+M*32); both dead before k_out writes y/feat (M <= N). ---
    __hip_bfloat16* e0    = (__hip_bfloat16*)d_out;
    __hip_bfloat16* e1raw = (__hip_bfloat16*)((float*)d_out + (size_t)N * 16);
    float* y    = (float*)d_out;
    float* feat = y + (size_t)N * 20;

    const int nblk = (N + 255) / 256;
    const int G = 2048;  // 8192 waves for grid-stride wave-per-row kernels

    hipMemsetAsync(stats, 0, 256 * sizeof(float), stream);

    k_xv<<<nblk, 256, 0, stream>>>(feats, nbr_f, W_sub, xv, N);
    k_subconv<32, 32, false, float, __hip_bfloat16>
        <<<G, 256, 0, stream>>>(xv, nullptr, nbr_f, W_e0, e0, N,
                                stats + 0, stats + 32);
    // xv dead; zero `down` (same region) for the atomic segment-sum
    hipMemsetAsync(down, 0, (size_t)M * 64 * sizeof(float), stream);
    k_fin<<<1, 64, 0, stream>>>(stats + 0, stats + 32, g0, b0,
                                stats + 256, stats + 288, 32, 1.f / (float)N);
    k_down<<<G, 256, 0, stream>>>(e0, parent, child, W_dn,
                                  stats + 256, stats + 288, down, N);
    k_subconv<64, 64, false, float, __hip_bfloat16>
        <<<G, 256, 0, stream>>>(down, nullptr, nbr_c, W_e1, e1raw, M,
                                stats + 64, stats + 128);
    k_fin<<<1, 64, 0, stream>>>(stats + 64, stats + 128, g1, b1,
                                stats + 320, stats + 384, 64, 1.f / (float)M);
    k_up<<<G, 256, 0, stream>>>(e1raw, parent, child, W_up,
                                stats + 320, stats + 384, up, N);
    k_subconv<64, 32, true, __hip_bfloat16, __hip_bfloat16>
        <<<G, 256, 0, stream>>>(e0, up, nbr_f, W_dec, decraw, N,
                                stats + 192, stats + 224);
    k_fin<<<1, 64, 0, stream>>>(stats + 192, stats + 224, g_o, b_o,
                                stats + 448, stats + 480, 32, 1.f / (float)N);
    k_out<<<nblk, 256, 0, stream>>>(decraw, stats + 448, stats + 480, W_lin, b_lin,
                                    y, feat, N);
}